// Round 1
// baseline (1817.186 us; speedup 1.0000x reference)
//
#include <hip/hip_runtime.h>
#include <hip/hip_bf16.h>

// Problem constants (B,DIM,H,W)=(4,256,64,64), DSTATE=64, EXPAND=2, DCONV=4
// DINNER=512, HEADDIM=64, NHEADS=8, DINPROJ=1160, CONVDIM=640, EPS=1e-5
#define EPSF 1e-5f

typedef unsigned short u16;

__device__ __forceinline__ float sigf(float x){ return 1.f/(1.f+__expf(-x)); }
__device__ __forceinline__ float siluf(float x){ return x/(1.f+__expf(-x)); }
__device__ __forceinline__ u16 f2bf(float x){ __hip_bfloat16 h = __float2bfloat16(x); return *reinterpret_cast<u16*>(&h); }
__device__ __forceinline__ float bf2f(u16 u){ __hip_bfloat16 h; *reinterpret_cast<u16*>(&h) = u; return __bfloat162float(h); }

// ---------------- K0: channel LayerNorm, x (B,C,H,W) -> xn (B,H,W,C) ----------------
__global__ __launch_bounds__(256) void k_ln(const float* __restrict__ x,
                                            const float* __restrict__ g,
                                            const float* __restrict__ b,
                                            float* __restrict__ xn){
  __shared__ float XL[256][65];
  __shared__ float red[2][4][64];
  __shared__ float muL[64], rsL[64];
  int blk = blockIdx.x; int bb = blk>>6, h = blk&63;
  int t = threadIdx.x;
  const float* xb = x + ((size_t)bb*256*4096) + h*64;
  for(int i=0;i<64;i++){ int idx = t + 256*i; int c = idx>>6, w = idx&63;
    XL[c][w] = xb[(size_t)c*4096 + w]; }
  __syncthreads();
  { int w = t & 63, q = t >> 6;
    float s1=0, s2=0;
    for(int c=q*64;c<q*64+64;c++){ float v = XL[c][w]; s1+=v; s2+=v*v; }
    red[0][q][w]=s1; red[1][q][w]=s2; }
  __syncthreads();
  if(t<64){ float a=0,c2=0;
    for(int q=0;q<4;q++){a+=red[0][q][t]; c2+=red[1][q][t];}
    float mu=a*(1.f/256.f); float var=c2*(1.f/256.f)-mu*mu;
    muL[t]=mu; rsL[t]=rsqrtf(var+EPSF); }
  __syncthreads();
  float* xnb = xn + (size_t)(bb*64+h)*64*256;
  for(int i=0;i<64;i++){ int idx = t + 256*i; int w = idx>>8, c = idx&255;
    float v = (XL[c][w]-muL[w])*rsL[w]*g[c]+b[c];
    xnb[w*256 + c] = v; }
}

// ---------------- K1: in-projection + conv(fwd & bwd) + silu + softplus ----------------
// grid (10 chunks, 256 seqs). chunk j-range = [chunk*128, chunk*128+128)
// cols [0,512)=z -> silu -> zg ; [512,1152)=xBC -> conv(both dirs)+silu -> xf/xb ; [1152,1160)=dt
__global__ __launch_bounds__(256) void k_proj(const float* __restrict__ xn,
    const float* __restrict__ Wi, const float* __restrict__ convw,
    const float* __restrict__ convb, const float* __restrict__ dtb,
    const float* __restrict__ alog,
    u16* __restrict__ zg, u16* __restrict__ xf, u16* __restrict__ xbw,
    float* __restrict__ dtp, float* __restrict__ dAo, int dirV){
  __shared__ float S[64][257];
  int chunk = blockIdx.x; int s = blockIdx.y;
  int bb = s>>6, r = s&63;
  int t = threadIdx.x;
  for(int i=0;i<64;i++){ int idx = t + 256*i; int l = idx>>8, c = idx&255;
    int row = dirV ? ((bb*64 + l)*64 + r) : ((bb*64 + r)*64 + l);
    S[l][c] = xn[(size_t)row*256 + c]; }
  __syncthreads();
  int jt = t&63, lt = t>>6;
  int jbase = chunk*128;
  int j0c = jbase + jt;      if(j0c>1159) j0c=1159;
  int j1c = jbase + jt + 64; if(j1c>1159) j1c=1159;
  const float* p0 = Wi + j0c;
  const float* p1 = Wi + j1c;
  float acc[16][2];
  #pragma unroll
  for(int i=0;i<16;i++){acc[i][0]=0.f;acc[i][1]=0.f;}
  #pragma unroll 4
  for(int k=0;k<256;k++){
    float w0 = p0[(size_t)k*1160];
    float w1 = p1[(size_t)k*1160];
    #pragma unroll
    for(int i=0;i<16;i++){ float sv = S[lt+4*i][k]; acc[i][0] += sv*w0; acc[i][1] += sv*w1; }
  }
  if(chunk < 4){
    #pragma unroll
    for(int i=0;i<16;i++){ int l = lt+4*i;
      zg[(s*64+l)*512 + jbase + jt     ] = f2bf(siluf(acc[i][0]));
      zg[(s*64+l)*512 + jbase + jt + 64] = f2bf(siluf(acc[i][1])); }
  } else if(chunk < 9){
    __syncthreads();                       // all GEMM reads of S done
    float* RAW = &S[0][0];                 // alias as [64][128]
    #pragma unroll
    for(int i=0;i<16;i++){ int l = lt+4*i;
      RAW[l*128 + jt]      = acc[i][0];
      RAW[l*128 + jt + 64] = acc[i][1]; }
    __syncthreads();
    #pragma unroll
    for(int jj=0;jj<2;jj++){
      int c = jbase + jt + 64*jj - 512;    // conv channel [0,640)
      float4 cw4 = *(const float4*)(convw + c*4);
      float cw[4] = {cw4.x, cw4.y, cw4.z, cw4.w};
      float cb = convb[c];
      #pragma unroll
      for(int i=0;i<16;i++){ int l = lt+4*i;
        float of = cb, ob = cb;
        #pragma unroll
        for(int k=0;k<4;k++){
          bool v = (l+k-3 >= 0);
          float vf = v ? RAW[(l-3+k)*128 + jt + 64*jj] : 0.f;   // causal
          float vb = v ? RAW[(66-l-k)*128 + jt + 64*jj] : 0.f;  // anticausal, reversed taps
          of += cw[k]*vf; ob += cw[k]*vb;
        }
        int gi = (s*64+l)*640 + c;
        xf [gi] = f2bf(siluf(of));
        xbw[gi] = f2bf(siluf(ob));
      }
    }
  } else {
    if(jt < 8){
      int hh = jt;
      float A = -expf(alog[hh]);
      float bias = dtb[hh];
      #pragma unroll
      for(int i=0;i<16;i++){ int l = lt+4*i;
        float v = acc[i][0] + bias;
        float sp = (v>20.f)? v : log1pf(expf(v));
        dtp[(s*64+l)*8 + hh] = sp;
        dAo[(s*64+l)*8 + hh] = expf(sp*A);
      }
    }
  }
}

// ---------------- K2: selective scan (fwd+bwd) + gate + RMSNorm + out-proj ----------------
// grid 256 (seq), block 1024 = 16 waves: wave = dir*8 + head
__global__ __launch_bounds__(1024) void k_scan(const u16* __restrict__ xf,
    const u16* __restrict__ xbw, const float* __restrict__ dtp,
    const float* __restrict__ dAi, const u16* __restrict__ zg,
    const float* __restrict__ dskip, const float* __restrict__ normw,
    const float* __restrict__ Wo, float* __restrict__ fout){
  __shared__ u16 Y[2][64][512];            // 128 KB: fwd/bwd y in ORIGINAL l order; Y[0] reused as U
  __shared__ float dtL[64][8], dAL[64][8];
  int s = blockIdx.x;
  int t = threadIdx.x;
  int wv = t>>6, p = t&63;
  int dirb = wv>>3, head = wv&7;
  if(t < 512){ int l = t>>3, hh = t&7;
    dtL[l][hh] = dtp[s*512 + t]; dAL[l][hh] = dAi[s*512 + t]; }
  __syncthreads();
  // ---- scan ----
  const u16* xb = (dirb? xbw : xf) + (size_t)s*64*640;
  float st[64];
  #pragma unroll
  for(int n=0;n<64;n++) st[n]=0.f;
  float dsk = dskip[head];
  #pragma unroll 1
  for(int step=0; step<64; step++){
    int lorig = dirb ? 63-step : step;
    float dtv = dtL[lorig][head];
    float dav = dAL[lorig][head];
    const u16* row = xb + step*640;
    float xh   = bf2f(row[head*64 + p]);
    float bval = bf2f(row[512 + p]);
    float cval = bf2f(row[576 + p]);
    float f = dtv * xh;
    float y0=0.f,y1=0.f,y2=0.f,y3=0.f;
    #pragma unroll
    for(int n=0;n<64;n+=4){
      float b0=__shfl(bval,n,64),   c0=__shfl(cval,n,64);
      float b1=__shfl(bval,n+1,64), c1=__shfl(cval,n+1,64);
      float b2=__shfl(bval,n+2,64), c2=__shfl(cval,n+2,64);
      float b3=__shfl(bval,n+3,64), c3=__shfl(cval,n+3,64);
      st[n]   = dav*st[n]   + f*b0; y0 += st[n]*c0;
      st[n+1] = dav*st[n+1] + f*b1; y1 += st[n+1]*c1;
      st[n+2] = dav*st[n+2] + f*b2; y2 += st[n+2]*c2;
      st[n+3] = dav*st[n+3] + f*b3; y3 += st[n+3]*c3;
    }
    float y = dsk*xh + ((y0+y1)+(y2+y3));
    Y[dirb][lorig][head*64+p] = f2bf(y);
  }
  __syncthreads();
  // ---- gate * silu(z), RMSNorm per direction, average into U (=Y[0]) ----
  #pragma unroll 1
  for(int i=0;i<4;i++){
    int l = wv + 16*i;
    float vf[8], vb[8];
    float ssf=0.f, ssb=0.f;
    #pragma unroll
    for(int j=0;j<8;j++){
      int fidx = p + 64*j;
      float zv = bf2f(zg[(s*64+l)*512 + fidx]);
      float a = bf2f(Y[0][l][fidx]) * zv;
      float c = bf2f(Y[1][l][fidx]) * zv;
      vf[j]=a; vb[j]=c; ssf += a*a; ssb += c*c;
    }
    #pragma unroll
    for(int off=32; off>=1; off>>=1){ ssf += __shfl_xor(ssf, off, 64); ssb += __shfl_xor(ssb, off, 64); }
    float rsf = rsqrtf(ssf*(1.f/512.f)+EPSF);
    float rsb = rsqrtf(ssb*(1.f/512.f)+EPSF);
    #pragma unroll
    for(int j=0;j<8;j++){
      int fidx = p + 64*j;
      Y[0][l][fidx] = f2bf(0.5f*(vf[j]*rsf + vb[j]*rsb)*normw[fidx]);
    }
  }
  __syncthreads();
  // ---- out-proj: fout[l][c] = sum_k U[l][k] * Wo[k][c] ----
  float acc[4][4];
  #pragma unroll
  for(int a=0;a<4;a++){
    #pragma unroll
    for(int q=0;q<4;q++) acc[a][q]=0.f;
  }
  int l0 = wv*4;
  #pragma unroll 4
  for(int k=0;k<512;k++){
    float u0 = bf2f(Y[0][l0+0][k]);
    float u1 = bf2f(Y[0][l0+1][k]);
    float u2 = bf2f(Y[0][l0+2][k]);
    float u3 = bf2f(Y[0][l0+3][k]);
    const float* wr = Wo + (size_t)k*256;
    #pragma unroll
    for(int q=0;q<4;q++){
      float wvv = wr[p + 64*q];
      acc[0][q] += u0*wvv; acc[1][q] += u1*wvv; acc[2][q] += u2*wvv; acc[3][q] += u3*wvv;
    }
  }
  #pragma unroll
  for(int li=0; li<4; li++){
    #pragma unroll
    for(int q=0;q<4;q++)
      fout[(size_t)(s*64 + l0+li)*256 + p + 64*q] = acc[li][q];
  }
}

// ---------------- K3: blend f_H/f_V, 1x1 conv, partial stats; y1 -> d_out ----------------
__global__ __launch_bounds__(256) void k_fuse(const float* __restrict__ fH,
    const float* __restrict__ fV, const float* __restrict__ Q1,
    const float* __restrict__ Sx, const float* __restrict__ W1,
    float* __restrict__ out, float* __restrict__ stats){
  __shared__ float fgL[64][260];           // aliased as y1 staging [256][65] (16640 floats each)
  __shared__ float W1L[256][65];
  __shared__ float asL[64], bsL[64];
  __shared__ float red[256];
  int blk = blockIdx.x; int bb = blk>>6, h = blk&63;
  int t = threadIdx.x;
  if(t<64){
    float qv = Q1[bb*4096 + h*64 + t];
    float sv = Sx[bb*4096 + h*64 + t];
    float al = sigf(qv);
    float sc = 0.5f + 0.5f*sv;
    asL[t] = al*sc; bsL[t] = (1.f-al)*sc;
  }
  __syncthreads();
  for(int i=0;i<64;i++){ int idx = t+256*i; int w = idx>>8, c = idx&255;
    float a = fH[(size_t)((bb*64+h)*64 + w)*256 + c];
    float b = fV[(size_t)((bb*64+w)*64 + h)*256 + c];
    fgL[w][c] = asL[w]*a + bsL[w]*b;
  }
  __syncthreads();
  float acc[64];
  #pragma unroll
  for(int w=0;w<64;w++) acc[w]=0.f;
  for(int c0=0;c0<256;c0+=64){
    for(int i=0;i<64;i++){ int idx=t+256*i; int o=idx>>6, cc=idx&63;
      W1L[o][cc] = W1[(size_t)o*256 + c0 + cc]; }
    __syncthreads();
    for(int cc=0;cc<64;cc++){
      float w1 = W1L[t][cc];
      #pragma unroll
      for(int w=0;w<64;w++) acc[w] += fgL[w][c0+cc]*w1;
    }
    __syncthreads();
  }
  float s1=0.f,s2=0.f;
  #pragma unroll
  for(int w=0;w<64;w++){ s1+=acc[w]; s2+=acc[w]*acc[w]; }
  red[t]=s1; __syncthreads();
  for(int off=128; off>=1; off>>=1){ if(t<off) red[t]+=red[t+off]; __syncthreads(); }
  if(t==0) stats[blk*2+0]=red[0];
  __syncthreads();
  red[t]=s2; __syncthreads();
  for(int off=128; off>=1; off>>=1){ if(t<off) red[t]+=red[t+off]; __syncthreads(); }
  if(t==0) stats[blk*2+1]=red[0];
  __syncthreads();
  float* yL = &fgL[0][0];                  // [256][65]
  for(int w=0;w<64;w++) yL[t*65 + w] = acc[w];
  __syncthreads();
  for(int i=0;i<64;i++){ int idx=t+256*i; int o=idx>>6, w=idx&63;
    out[(size_t)((bb*256+o)*64 + h)*64 + w] = yL[o*65 + w]; }
}

// ---------------- K4: per-batch global norm + exact GELU, in place on d_out ----------------
__global__ __launch_bounds__(256) void k_final(float* __restrict__ out,
    const float* __restrict__ stats, const float* __restrict__ gg,
    const float* __restrict__ gb){
  __shared__ float red[64][2];
  __shared__ float mv[2];
  int blk = blockIdx.x; int bb = blk>>6, h = blk&63;
  int t = threadIdx.x;
  if(t<64){ red[t][0] = stats[(bb*64+t)*2+0]; red[t][1] = stats[(bb*64+t)*2+1]; }
  __syncthreads();
  if(t==0){
    float s1=0.f,s2=0.f;
    for(int i=0;i<64;i++){ s1+=red[i][0]; s2+=red[i][1]; }
    float mu = s1*(1.f/1048576.f);
    float var = s2*(1.f/1048576.f) - mu*mu;
    mv[0]=mu; mv[1]=rsqrtf(var+EPSF);
  }
  __syncthreads();
  float mu = mv[0], rs = mv[1];
  for(int i=0;i<64;i++){ int idx=t+256*i; int o=idx>>6, w=idx&63;
    size_t gidx = (size_t)((bb*256+o)*64+h)*64+w;
    float v = out[gidx];
    float yn = (v-mu)*rs*gg[o] + gb[o];
    out[gidx] = 0.5f*yn*(1.f+erff(yn*0.70710678118654752f));
  }
}

extern "C" void kernel_launch(void* const* d_in, const int* in_sizes, int n_in,
                              void* d_out, int out_size, void* d_ws, size_t ws_size,
                              hipStream_t stream) {
  const float* x     = (const float*)d_in[0];
  const float* Q1    = (const float*)d_in[1];
  // d_in[2] = Q2 : unused by the reference
  const float* Sx    = (const float*)d_in[3];
  const float* lng   = (const float*)d_in[4];
  const float* lnb   = (const float*)d_in[5];
  const float* Wi    = (const float*)d_in[6];
  const float* convw = (const float*)d_in[7];
  const float* convb = (const float*)d_in[8];
  const float* dtb   = (const float*)d_in[9];
  const float* alog  = (const float*)d_in[10];
  const float* dskip = (const float*)d_in[11];
  const float* normw = (const float*)d_in[12];
  const float* Wo    = (const float*)d_in[13];
  const float* gg    = (const float*)d_in[14];
  const float* gb    = (const float*)d_in[15];
  const float* W1    = (const float*)d_in[16];
  float* out = (float*)d_out;
  char* ws = (char*)d_ws;

  // ws layout (needs ~105 MiB):
  // xn 16MB | fH 16MB | fV 16MB | zg bf16 16MB | xf bf16 20MB | xb bf16 20MB | dtp 0.5MB | dA 0.5MB | stats 2KB
  float* xn  = (float*)(ws);
  float* fH  = (float*)(ws + 16777216);
  float* fV  = (float*)(ws + 2*16777216);
  u16*   zgb = (u16*)  (ws + 3*16777216);
  u16*   xfb = (u16*)  (ws + 4*16777216);
  u16*   xbb = (u16*)  (ws + (size_t)4*16777216 + 20971520);
  float* dtp = (float*)(ws + (size_t)4*16777216 + 2*(size_t)20971520);
  float* dAr = (float*)(ws + (size_t)4*16777216 + 2*(size_t)20971520 + 524288);
  float* stats=(float*)(ws + (size_t)4*16777216 + 2*(size_t)20971520 + 2*(size_t)524288);

  k_ln<<<256, 256, 0, stream>>>(x, lng, lnb, xn);
  for(int dir=0; dir<2; dir++){
    k_proj<<<dim3(10,256), 256, 0, stream>>>(xn, Wi, convw, convb, dtb, alog,
                                             zgb, xfb, xbb, dtp, dAr, dir);
    k_scan<<<256, 1024, 0, stream>>>(xfb, xbb, dtp, dAr, zgb, dskip, normw, Wo,
                                     dir ? fV : fH);
  }
  k_fuse<<<256, 256, 0, stream>>>(fH, fV, Q1, Sx, W1, out, stats);
  k_final<<<256, 256, 0, stream>>>(out, stats, gg, gb);
}